// Round 1
// baseline (2851.502 us; speedup 1.0000x reference)
//
#include <hip/hip_runtime.h>
#include <math.h>

// Sinkhorn EMD loss, B=32, N=1024, 3-D points, EPS=0.02, 50 iters.
// Strategy: recompute C_ij on the fly from points (compute-bound, ~2 trans +
// ~8 VALU per element); one wave per row, 16 logits per lane in registers,
// two-pass logsumexp in exp2 domain. 100 half-iteration launches + final
// <P,C> reduction, all graph-capture safe.

#define BATCH 32
#define NPT 1024
#define EPS 0.02f
#define ITERS 50

static __device__ __forceinline__ float wave_max(float v) {
    #pragma unroll
    for (int off = 32; off > 0; off >>= 1)
        v = fmaxf(v, __shfl_xor(v, off, 64));
    return v;
}
static __device__ __forceinline__ float wave_sum(float v) {
    #pragma unroll
    for (int off = 32; off > 0; off >>= 1)
        v += __shfl_xor(v, off, 64);
    return v;
}

// One half Sinkhorn update: out_pot[b][i] =
//   EPS * (log_marg - logsumexp_j((col_pot[b][j] - C(b,i,j)) / EPS))
// where C(b,i,j) = sqrt(|row_pts[b][i] - col_pts[b][j]|^2 + 1e-12).
// 4 waves/WG, 4 rows/wave -> 16 rows per WG, 64 WGs per batch.
__global__ __launch_bounds__(256) void sinkhorn_half(
    const float* __restrict__ row_pts,   // [B][N][3]
    const float* __restrict__ col_pts,   // [B][N][3]
    const float* __restrict__ col_pot,   // [B][N]
    float* __restrict__ out_pot)         // [B][N]
{
    constexpr float LOG2E = 1.4426950408889634f;
    constexpr float LN2   = 0.6931471805599453f;
    constexpr float K2    = LOG2E / EPS;             // exp2-domain scale
    constexpr float LOGMARG = -6.93147180559945309f; // ln(1/1024)

    __shared__ float4 cols[NPT];  // {x, y, z, pot*K2}  16 KB

    const int wg_per_batch = NPT / 16;  // 64
    const int b  = blockIdx.x / wg_per_batch;
    const int wg = blockIdx.x % wg_per_batch;
    const int tid = threadIdx.x;

    const float* cp = col_pts + (size_t)b * NPT * 3;
    const float* pp = col_pot + (size_t)b * NPT;
    #pragma unroll
    for (int r = 0; r < 4; ++r) {
        int j = tid + 256 * r;
        cols[j] = make_float4(cp[3*j], cp[3*j+1], cp[3*j+2], pp[j] * K2);
    }
    __syncthreads();

    const int wave = tid >> 6;
    const int lane = tid & 63;
    const float* rp = row_pts + (size_t)b * NPT * 3;
    float* op = out_pot + (size_t)b * NPT;

    #pragma unroll 1
    for (int r = 0; r < 4; ++r) {
        const int i = wg * 16 + wave * 4 + r;
        const float tx = rp[3*i], ty = rp[3*i+1], tz = rp[3*i+2];

        float xv[16];
        float m = -3.4e38f;
        #pragma unroll
        for (int k = 0; k < 16; ++k) {
            float4 c = cols[lane + 64 * k];
            float dx = tx - c.x, dy = ty - c.y, dz = tz - c.z;
            float d2 = fmaf(dx, dx, fmaf(dy, dy, fmaf(dz, dz, 1e-12f)));
            float C = sqrtf(d2);
            float x = fmaf(C, -K2, c.w);   // (pot_j - C)/eps in exp2 domain
            xv[k] = x;
            m = fmaxf(m, x);
        }
        m = wave_max(m);
        float s = 0.f;
        #pragma unroll
        for (int k = 0; k < 16; ++k)
            s += exp2f(xv[k] - m);
        s = wave_sum(s);
        if (lane == 0) {
            float lse = (m + log2f(s)) * LN2;  // natural-log LSE
            op[i] = EPS * (LOGMARG - lse);
        }
    }
}

// Final: acc += sum_ij C_ij * exp((f_i + g_j - C_ij)/EPS)
__global__ __launch_bounds__(256) void emd_final(
    const float* __restrict__ t_pts,   // [B][N][3]
    const float* __restrict__ s_pts,   // [B][N][3]
    const float* __restrict__ f,       // [B][N]
    const float* __restrict__ g,       // [B][N]
    float* __restrict__ acc)
{
    constexpr float LOG2E = 1.4426950408889634f;
    constexpr float K2    = LOG2E / EPS;

    __shared__ float4 cols[NPT];  // {x, y, z, g*K2}

    const int wg_per_batch = NPT / 16;
    const int b  = blockIdx.x / wg_per_batch;
    const int wg = blockIdx.x % wg_per_batch;
    const int tid = threadIdx.x;

    const float* cp = s_pts + (size_t)b * NPT * 3;
    const float* gp = g + (size_t)b * NPT;
    #pragma unroll
    for (int r = 0; r < 4; ++r) {
        int j = tid + 256 * r;
        cols[j] = make_float4(cp[3*j], cp[3*j+1], cp[3*j+2], gp[j] * K2);
    }
    __syncthreads();

    const int wave = tid >> 6;
    const int lane = tid & 63;
    const float* rp = t_pts + (size_t)b * NPT * 3;
    const float* fp = f + (size_t)b * NPT;

    float local = 0.f;
    #pragma unroll 1
    for (int r = 0; r < 4; ++r) {
        const int i = wg * 16 + wave * 4 + r;
        const float tx = rp[3*i], ty = rp[3*i+1], tz = rp[3*i+2];
        const float fs = fp[i] * K2;
        #pragma unroll
        for (int k = 0; k < 16; ++k) {
            float4 c = cols[lane + 64 * k];
            float dx = tx - c.x, dy = ty - c.y, dz = tz - c.z;
            float d2 = fmaf(dx, dx, fmaf(dy, dy, fmaf(dz, dz, 1e-12f)));
            float C = sqrtf(d2);
            float arg = fmaf(C, -K2, fs + c.w);
            float p = exp2f(arg);
            local = fmaf(p, C, local);
        }
    }
    local = wave_sum(local);
    if (lane == 0)
        atomicAdd(acc, local);
}

__global__ void finalize_kernel(const float* __restrict__ acc,
                                float* __restrict__ out)
{
    // mean over batch, then / N
    out[0] = acc[0] * (1.0f / ((float)BATCH * (float)NPT));
}

extern "C" void kernel_launch(void* const* d_in, const int* in_sizes, int n_in,
                              void* d_out, int out_size, void* d_ws, size_t ws_size,
                              hipStream_t stream) {
    const float* tmpl = (const float*)d_in[0];   // [32,1024,3]
    const float* src  = (const float*)d_in[1];   // [32,1024,3]
    float* out = (float*)d_out;

    float* f   = (float*)d_ws;               // [B*N]
    float* g   = f + BATCH * NPT;            // [B*N]
    float* acc = g + BATCH * NPT;            // [1]

    // g must start at 0 (ws is poisoned before every call); acc accumulates.
    hipMemsetAsync(g, 0, BATCH * NPT * sizeof(float), stream);
    hipMemsetAsync(acc, 0, sizeof(float), stream);

    dim3 grid(BATCH * (NPT / 16));  // 2048 WGs
    dim3 block(256);

    for (int it = 0; it < ITERS; ++it) {
        // f = eps*(logmarg - LSE_j((g_j - C_ij)/eps))   rows = template
        sinkhorn_half<<<grid, block, 0, stream>>>(tmpl, src, g, f);
        // g = eps*(logmarg - LSE_i((f_i - C_ij)/eps))   rows = source
        sinkhorn_half<<<grid, block, 0, stream>>>(src, tmpl, f, g);
    }
    emd_final<<<grid, block, 0, stream>>>(tmpl, src, f, g, acc);
    finalize_kernel<<<1, 1, 0, stream>>>(acc, out);
}

// Round 5
// 1342.673 us; speedup vs baseline: 2.1237x; 2.1237x over previous
//
#include <hip/hip_runtime.h>
#include <math.h>

// Sinkhorn EMD loss, B=32, N=1024, 3-D points, EPS=0.02, 50 iters.
// R1: single-pass LSE with block-level max shift (no per-row max pass),
// 4-row register tiling per wave (each LDS float4 feeds 4 rows),
// raw v_sqrt/v_exp builtins, 1 atomic per WG in the final reduction.

#define BATCH 32
#define NPT 1024
#define EPS 0.02f
#define ITERS 50

static __device__ __forceinline__ float wave_max(float v) {
    #pragma unroll
    for (int off = 32; off > 0; off >>= 1)
        v = fmaxf(v, __shfl_xor(v, off, 64));
    return v;
}
static __device__ __forceinline__ float wave_sum(float v) {
    #pragma unroll
    for (int off = 32; off > 0; off >>= 1)
        v += __shfl_xor(v, off, 64);
    return v;
}

// out_pot[b][i] = EPS*(log_marg - logsumexp_j((col_pot[b][j] - C(b,i,j))/EPS))
// C = sqrt(|row_pts_i - col_pts_j|^2 + 1e-12).
// 4 waves/WG, each wave owns 4 rows processed SIMULTANEOUSLY over the k-loop.
__global__ __launch_bounds__(256) void sinkhorn_half(
    const float* __restrict__ row_pts,   // [B][N][3]
    const float* __restrict__ col_pts,   // [B][N][3]
    const float* __restrict__ col_pot,   // [B][N]
    float* __restrict__ out_pot)         // [B][N]
{
    constexpr float LOG2E = 1.4426950408889634f;
    constexpr float LN2   = 0.6931471805599453f;
    constexpr float K2    = LOG2E / EPS;             // exp2-domain scale
    constexpr float LOGMARG = -6.93147180559945309f; // ln(1/1024)

    __shared__ float4 cols[NPT];   // {x, y, z, pot*K2 - S}  16 KB
    __shared__ float  wmax[4];

    const int wg_per_batch = NPT / 16;  // 64
    const int b  = blockIdx.x / wg_per_batch;
    const int wg = blockIdx.x % wg_per_batch;
    const int tid = threadIdx.x;
    const int wave = tid >> 6;
    const int lane = tid & 63;

    const float* cp = col_pts + (size_t)b * NPT * 3;
    const float* pp = col_pot + (size_t)b * NPT;

    // Stage cols + compute block max of pot*K2 for the LSE shift.
    float lmax = -3.4e38f;
    #pragma unroll
    for (int r = 0; r < 4; ++r) {
        int j = tid + 256 * r;
        float w = pp[j] * K2;
        cols[j] = make_float4(cp[3*j], cp[3*j+1], cp[3*j+2], w);
        lmax = fmaxf(lmax, w);
    }
    lmax = wave_max(lmax);
    if (lane == 0) wmax[wave] = lmax;
    __syncthreads();
    // Shift S: terms exp2(pot*K2 - C*K2 - S) <= 2^60 (no overflow) and the
    // argmax-j term >= 2^(60 - sqrt(3)*K2) = 2^-64.9 (no fatal underflow).
    const float S = fmaxf(fmaxf(wmax[0], wmax[1]), fmaxf(wmax[2], wmax[3])) - 60.0f;
    #pragma unroll
    for (int r = 0; r < 4; ++r) {
        int j = tid + 256 * r;
        reinterpret_cast<float*>(&cols[j])[3] -= S;
    }
    __syncthreads();

    const float* rp = row_pts + (size_t)b * NPT * 3;
    float* op = out_pot + (size_t)b * NPT;

    const int i0 = wg * 16 + wave * 4;
    float tx[4], ty[4], tz[4], s[4];
    #pragma unroll
    for (int r = 0; r < 4; ++r) {
        tx[r] = rp[3*(i0+r)]; ty[r] = rp[3*(i0+r)+1]; tz[r] = rp[3*(i0+r)+2];
        s[r] = 0.f;
    }

    #pragma unroll 4
    for (int k = 0; k < 16; ++k) {
        float4 c = cols[lane + 64 * k];
        #pragma unroll
        for (int r = 0; r < 4; ++r) {
            float dx = tx[r] - c.x, dy = ty[r] - c.y, dz = tz[r] - c.z;
            float d2 = fmaf(dx, dx, fmaf(dy, dy, fmaf(dz, dz, 1e-12f)));
            float C  = __builtin_amdgcn_sqrtf(d2);
            float arg = fmaf(C, -K2, c.w);
            s[r] += __builtin_amdgcn_exp2f(arg);
        }
    }
    #pragma unroll
    for (int r = 0; r < 4; ++r) s[r] = wave_sum(s[r]);
    if (lane == 0) {
        #pragma unroll
        for (int r = 0; r < 4; ++r) {
            float lse = (S + __builtin_amdgcn_logf(s[r])) * LN2;  // natural-log LSE
            op[i0 + r] = EPS * (LOGMARG - lse);
        }
    }
}

// acc += sum_ij C_ij * exp((f_i + g_j - C_ij)/EPS)
__global__ __launch_bounds__(256) void emd_final(
    const float* __restrict__ t_pts,   // [B][N][3]
    const float* __restrict__ s_pts,   // [B][N][3]
    const float* __restrict__ f,       // [B][N]
    const float* __restrict__ g,       // [B][N]
    float* __restrict__ acc)
{
    constexpr float LOG2E = 1.4426950408889634f;
    constexpr float K2    = LOG2E / EPS;

    __shared__ float4 cols[NPT];   // {x, y, z, g*K2 - S}
    __shared__ float  wmax[4];
    __shared__ float  accsm[4];

    const int wg_per_batch = NPT / 16;
    const int b  = blockIdx.x / wg_per_batch;
    const int wg = blockIdx.x % wg_per_batch;
    const int tid = threadIdx.x;
    const int wave = tid >> 6;
    const int lane = tid & 63;

    const float* cp = s_pts + (size_t)b * NPT * 3;
    const float* gp = g + (size_t)b * NPT;

    float lmax = -3.4e38f;
    #pragma unroll
    for (int r = 0; r < 4; ++r) {
        int j = tid + 256 * r;
        float w = gp[j] * K2;
        cols[j] = make_float4(cp[3*j], cp[3*j+1], cp[3*j+2], w);
        lmax = fmaxf(lmax, w);
    }
    lmax = wave_max(lmax);
    if (lane == 0) wmax[wave] = lmax;
    __syncthreads();
    const float S = fmaxf(fmaxf(wmax[0], wmax[1]), fmaxf(wmax[2], wmax[3])) - 60.0f;
    #pragma unroll
    for (int r = 0; r < 4; ++r) {
        int j = tid + 256 * r;
        reinterpret_cast<float*>(&cols[j])[3] -= S;
    }
    __syncthreads();

    const float* rp = t_pts + (size_t)b * NPT * 3;
    const float* fp = f + (size_t)b * NPT;

    const int i0 = wg * 16 + wave * 4;
    float tx[4], ty[4], tz[4], loc[4];
    #pragma unroll
    for (int r = 0; r < 4; ++r) {
        tx[r] = rp[3*(i0+r)]; ty[r] = rp[3*(i0+r)+1]; tz[r] = rp[3*(i0+r)+2];
        loc[r] = 0.f;
    }

    #pragma unroll 4
    for (int k = 0; k < 16; ++k) {
        float4 c = cols[lane + 64 * k];
        #pragma unroll
        for (int r = 0; r < 4; ++r) {
            float dx = tx[r] - c.x, dy = ty[r] - c.y, dz = tz[r] - c.z;
            float d2 = fmaf(dx, dx, fmaf(dy, dy, fmaf(dz, dz, 1e-12f)));
            float C  = __builtin_amdgcn_sqrtf(d2);
            float p  = __builtin_amdgcn_exp2f(fmaf(C, -K2, c.w));
            loc[r] = fmaf(p, C, loc[r]);   // sum_j C * 2^(g K2 - S - C K2)
        }
    }
    // per-row scale 2^(f_i K2 + S), summed within the wave
    float wtot = 0.f;
    #pragma unroll
    for (int r = 0; r < 4; ++r) {
        float sc = __builtin_amdgcn_exp2f(fmaf(fp[i0 + r], K2, S));
        wtot = fmaf(sc, loc[r], wtot);
    }
    wtot = wave_sum(wtot);
    if (lane == 0) accsm[wave] = wtot;
    __syncthreads();
    if (tid == 0) {
        float t = accsm[0] + accsm[1] + accsm[2] + accsm[3];
        atomicAdd(acc, t);
    }
}

__global__ void finalize_kernel(const float* __restrict__ acc,
                                float* __restrict__ out)
{
    out[0] = acc[0] * (1.0f / ((float)BATCH * (float)NPT));
}

extern "C" void kernel_launch(void* const* d_in, const int* in_sizes, int n_in,
                              void* d_out, int out_size, void* d_ws, size_t ws_size,
                              hipStream_t stream) {
    const float* tmpl = (const float*)d_in[0];   // [32,1024,3]
    const float* src  = (const float*)d_in[1];   // [32,1024,3]
    float* out = (float*)d_out;

    float* f   = (float*)d_ws;               // [B*N]
    float* g   = f + BATCH * NPT;            // [B*N]
    float* acc = g + BATCH * NPT;            // [1]

    hipMemsetAsync(g, 0, BATCH * NPT * sizeof(float), stream);
    hipMemsetAsync(acc, 0, sizeof(float), stream);

    dim3 grid(BATCH * (NPT / 16));  // 2048 WGs
    dim3 block(256);

    for (int it = 0; it < ITERS; ++it) {
        sinkhorn_half<<<grid, block, 0, stream>>>(tmpl, src, g, f);
        sinkhorn_half<<<grid, block, 0, stream>>>(src, tmpl, f, g);
    }
    emd_final<<<grid, block, 0, stream>>>(tmpl, src, f, g, acc);
    finalize_kernel<<<1, 1, 0, stream>>>(acc, out);
}